// Round 14
// baseline (410.873 us; speedup 1.0000x reference)
//
#include <hip/hip_runtime.h>
#include <hip/hip_bf16.h>

// ---------------- constants (match reference) ----------------
#define DIM_IN 1000
#define HEADS 8
#define HID 8
#define DIM_OUT 32
#define NEG_SLOPE 0.2f
#define EPAD 64

typedef __attribute__((ext_vector_type(4))) float f32x4;
typedef __attribute__((ext_vector_type(8))) short s16x8;

__device__ __forceinline__ unsigned bf16rne(float f) {
    unsigned u = __float_as_uint(f);
    return (u + 0x7FFFu + ((u >> 16) & 1u)) >> 16;
}
__device__ __forceinline__ unsigned pack2(float lo, float hi) {
    return bf16rne(lo) | (bf16rne(hi) << 16);
}
__device__ __forceinline__ float bflo(unsigned u) { return __uint_as_float(u << 16); }
__device__ __forceinline__ float bfhi(unsigned u) { return __uint_as_float(u & 0xFFFF0000u); }
__device__ __forceinline__ float bf1(ushort u) { return __uint_as_float((unsigned)u << 16); }

// ---------------- fused pre-pack: wpack (64 blk) | w3pack (8 blk) | wtilde (2 blk) ----
__global__ __launch_bounds__(256) void pack_all(
    const float* __restrict__ W1, const float* __restrict__ W2,
    const float* __restrict__ W3, const float* __restrict__ as3,
    const float* __restrict__ ad3, ushort* __restrict__ wpack,
    ushort* __restrict__ w3pack, float* __restrict__ wts,
    float* __restrict__ wtd)
{
    int b = blockIdx.x;
    if (b < 64) {
        int t = b * 256 + threadIdx.x;   // 0..16383
        int lane = t & 63;
        int ctg = (t >> 6) & 7;
        int kt = t >> 9;
        int c = ctg * 16 + (lane & 15);
        int kbase = kt * 32 + (lane >> 4) * 8;
        ushort v[8] __attribute__((aligned(16)));
#pragma unroll
        for (int j = 0; j < 8; j++) {
            int k = kbase + j;
            float w = 0.f;
            if (k < DIM_IN) w = (c < 64) ? W1[(size_t)k * 64 + c] : W2[(size_t)k * 64 + (c - 64)];
            v[j] = (ushort)bf16rne(w);
        }
        *(uint4*)&wpack[(size_t)t * 8] = *(const uint4*)v;
    } else if (b < 72) {
        int t = (b - 64) * 256 + threadIdx.x;   // 0..2047
        int lane = t & 63;
        int ctg = (t >> 6) & 15;
        int kt = t >> 10;
        int c = ctg * 16 + (lane & 15);
        int kbase = kt * 32 + (lane >> 4) * 8;
        ushort v[8] __attribute__((aligned(16)));
#pragma unroll
        for (int j = 0; j < 8; j++)
            v[j] = (ushort)bf16rne(W3[(size_t)(kbase + j) * 256 + c]);
        *(uint4*)&w3pack[(size_t)t * 8] = *(const uint4*)v;
    } else {
        int t = (b - 72) * 256 + threadIdx.x;   // 0..511
        if (t >= 512) return;
        int h = t >> 6, k = t & 63;
        float s = 0.f, d = 0.f;
#pragma unroll
        for (int c = 0; c < 32; c++) {
            float w = W3[(size_t)k * 256 + h * 32 + c];
            s += w * as3[h * 32 + c];
            d += w * ad3[h * 32 + c];
        }
        wts[h * 64 + k] = s;
        wtd[h * 64 + k] = d;
    }
}

// ---------------- zero deg + esrc pad in one launch ----------------
__global__ __launch_bounds__(256) void zero_init(
    int* __restrict__ deg, int* __restrict__ esrc_pad, int N)
{
    int i = blockIdx.x * 256 + threadIdx.x;
    if (i < N) deg[i] = 0;
    if (i < EPAD) esrc_pad[i] = 0;
}

// ---------------- GEMM1 (MFMA bf16): x[N,1000] @ [W1|W2a] -> hp1b(bf16), p2(f32) ----
__global__ __launch_bounds__(256) void gemm1_mfma(
    const float* __restrict__ x, const ushort* __restrict__ wpack,
    ushort* __restrict__ hp1b, float* __restrict__ p2, int N)
{
    __shared__ __align__(16) ushort a_lds[2][64 * 32];
    const int tid = threadIdx.x;
    const int lane = tid & 63;
    const int wc = tid >> 6;
    const int rowbase = blockIdx.x * 64;

    const int srow = tid >> 2;
    const int skg = tid & 3;
    const int sgr = rowbase + srow;
    const int sidx = ((srow >> 4) * 64 + skg * 16 + (srow & 15)) * 8;

    f32x4 acc[4][2];
#pragma unroll
    for (int i = 0; i < 4; i++)
#pragma unroll
        for (int j = 0; j < 2; j++) acc[i][j] = (f32x4){0.f, 0.f, 0.f, 0.f};

    float4 s0, s1;
    auto load_stage = [&](int t) {
        int k0 = t * 32 + skg * 8;
        s0 = make_float4(0.f, 0.f, 0.f, 0.f);
        s1 = make_float4(0.f, 0.f, 0.f, 0.f);
        if (sgr < N && k0 + 8 <= DIM_IN) {
            const float* p = &x[(size_t)sgr * DIM_IN + k0];
            s0 = *(const float4*)p;
            s1 = *(const float4*)(p + 4);
        }
    };
    auto store_stage = [&](int buf) {
        uint4 w;
        w.x = pack2(s0.x, s0.y);
        w.y = pack2(s0.z, s0.w);
        w.z = pack2(s1.x, s1.y);
        w.w = pack2(s1.z, s1.w);
        *(uint4*)&a_lds[buf][sidx] = w;
    };

    load_stage(0);
    store_stage(0);
    __syncthreads();

    const s16x8* wp = (const s16x8*)wpack;
    for (int t = 0; t < 32; t++) {
        int cur = t & 1;
        if (t + 1 < 32) load_stage(t + 1);
        s16x8 bf0 = wp[(size_t)(t * 8 + wc * 2 + 0) * 64 + lane];
        s16x8 bf1 = wp[(size_t)(t * 8 + wc * 2 + 1) * 64 + lane];
        s16x8 af0 = *(const s16x8*)&a_lds[cur][(0 * 64 + lane) * 8];
        s16x8 af1 = *(const s16x8*)&a_lds[cur][(1 * 64 + lane) * 8];
        s16x8 af2 = *(const s16x8*)&a_lds[cur][(2 * 64 + lane) * 8];
        s16x8 af3 = *(const s16x8*)&a_lds[cur][(3 * 64 + lane) * 8];
        acc[0][0] = __builtin_amdgcn_mfma_f32_16x16x32_bf16(af0, bf0, acc[0][0], 0, 0, 0);
        acc[0][1] = __builtin_amdgcn_mfma_f32_16x16x32_bf16(af0, bf1, acc[0][1], 0, 0, 0);
        acc[1][0] = __builtin_amdgcn_mfma_f32_16x16x32_bf16(af1, bf0, acc[1][0], 0, 0, 0);
        acc[1][1] = __builtin_amdgcn_mfma_f32_16x16x32_bf16(af1, bf1, acc[1][1], 0, 0, 0);
        acc[2][0] = __builtin_amdgcn_mfma_f32_16x16x32_bf16(af2, bf0, acc[2][0], 0, 0, 0);
        acc[2][1] = __builtin_amdgcn_mfma_f32_16x16x32_bf16(af2, bf1, acc[2][1], 0, 0, 0);
        acc[3][0] = __builtin_amdgcn_mfma_f32_16x16x32_bf16(af3, bf0, acc[3][0], 0, 0, 0);
        acc[3][1] = __builtin_amdgcn_mfma_f32_16x16x32_bf16(af3, bf1, acc[3][1], 0, 0, 0);
        if (t + 1 < 32) store_stage(cur ^ 1);
        __syncthreads();
    }

    const int colbase = wc * 32;
#pragma unroll
    for (int rt = 0; rt < 4; rt++) {
        int gr = rowbase + rt * 16 + ((lane >> 4) * 4);
#pragma unroll
        for (int ctl = 0; ctl < 2; ctl++) {
            int c = colbase + ctl * 16 + (lane & 15);
#pragma unroll
            for (int reg = 0; reg < 4; reg++) {
                int r = gr + reg;
                if (r >= N) continue;
                float v = acc[rt][ctl][reg];
                if (c < 64) hp1b[(size_t)r * 64 + c] = (ushort)bf16rne(v);
                else        p2[(size_t)r * 64 + (c - 64)] = v;
            }
        }
    }
}

// ---------------- GEMM3 (MFMA bf16): h3pb[N,256] = h2b[N,64] @ W3 ----------------
__global__ __launch_bounds__(256) void gemm3_mfma(
    const ushort* __restrict__ h2b, const ushort* __restrict__ w3pack,
    ushort* __restrict__ h3pb, int N)
{
    const int tid = threadIdx.x;
    const int lane = tid & 63;
    const int wc = tid >> 6;
    const int rowbase = blockIdx.x * 16;
    const int arow = rowbase + (lane & 15);

    f32x4 acc[4];
#pragma unroll
    for (int i = 0; i < 4; i++) acc[i] = (f32x4){0.f, 0.f, 0.f, 0.f};

    const s16x8* wp = (const s16x8*)w3pack;
#pragma unroll
    for (int kt = 0; kt < 2; kt++) {
        s16x8 af = (s16x8){0, 0, 0, 0, 0, 0, 0, 0};
        if (arow < N)
            af = *(const s16x8*)&h2b[(size_t)arow * 64 + kt * 32 + (lane >> 4) * 8];
#pragma unroll
        for (int ct = 0; ct < 4; ct++) {
            s16x8 bf = wp[(size_t)(kt * 16 + wc * 4 + ct) * 64 + lane];
            acc[ct] = __builtin_amdgcn_mfma_f32_16x16x32_bf16(af, bf, acc[ct], 0, 0, 0);
        }
    }
#pragma unroll
    for (int ct = 0; ct < 4; ct++) {
        int col = wc * 64 + ct * 16 + (lane & 15);
        int gr = rowbase + (lane >> 4) * 4;
#pragma unroll
        for (int reg = 0; reg < 4; reg++) {
            int r = gr + reg;
            if (r < N) h3pb[(size_t)r * 256 + col] = (ushort)bf16rne(acc[ct][reg]);
        }
    }
}

// ---------------- small GEMM, K=64, NC=64: h2pre_b = bf16(p2 + h1@W2b) ----------------
__global__ __launch_bounds__(256) void gemm_k64_n64_acc(
    const float* __restrict__ A, const float* __restrict__ W,
    const float* __restrict__ P, ushort* __restrict__ outb, int N)
{
    __shared__ float as_[16][65];
    const int tid = threadIdx.x;
    const int rb = blockIdx.x * 16;
#pragma unroll
    for (int i = 0; i < 4; i++) {
        int idx = tid + i * 256;
        int r = idx >> 6, c = idx & 63;
        int gr = rb + r;
        as_[r][c] = (gr < N) ? A[(size_t)gr * 64 + c] : 0.f;
    }
    __syncthreads();
    const int row = tid >> 4;
    const int col = (tid & 15) * 4;
    float4 acc = {0, 0, 0, 0};
#pragma unroll 8
    for (int k = 0; k < 64; k++) {
        float a = as_[row][k];
        float4 w = *(const float4*)&W[k * 64 + col];
        acc.x += a * w.x; acc.y += a * w.y; acc.z += a * w.z; acc.w += a * w.w;
    }
    int gr = rb + row;
    if (gr < N) {
        float4 p = *(const float4*)&P[(size_t)gr * 64 + col];
        float v0 = p.x + acc.x, v1 = p.y + acc.y, v2 = p.z + acc.z, v3 = p.w + acc.w;
        *(uint*)&outb[(size_t)gr * 64 + col] = pack2(v0, v1);
        *(uint*)&outb[(size_t)gr * 64 + col + 2] = pack2(v2, v3);
    }
}

// ---------------- attention dots, bf16 rows, per-head C=8 ----------------
__global__ __launch_bounds__(256) void attn_dots_b8(
    const ushort* __restrict__ hb, const float* __restrict__ a_s,
    const float* __restrict__ a_d, float* __restrict__ als,
    float* __restrict__ ald, int NH)
{
    int i = blockIdx.x * blockDim.x + threadIdx.x;   // node*8 + head
    if (i >= NH) return;
    int head = i & 7;
    uint4 q = *(const uint4*)&hb[(size_t)i * 8];
    float f[8] = {bflo(q.x), bfhi(q.x), bflo(q.y), bfhi(q.y),
                  bflo(q.z), bfhi(q.z), bflo(q.w), bfhi(q.w)};
    const float* ap = a_s + head * 8;
    const float* dp = a_d + head * 8;
    float s = 0.f, d = 0.f;
#pragma unroll
    for (int c = 0; c < 8; c++) { s += f[c] * ap[c]; d += f[c] * dp[c]; }
    als[i] = s; ald[i] = d;
}

// ---------------- layer-3 attention dots from bf16 h2 via wtilde ----------------
__global__ __launch_bounds__(256) void attn_dots_w(
    const ushort* __restrict__ h2b, const float* __restrict__ wts,
    const float* __restrict__ wtd, float* __restrict__ als,
    float* __restrict__ ald, int NH)
{
    int i = blockIdx.x * blockDim.x + threadIdx.x;
    if (i >= NH) return;
    int head = i & 7, node = i >> 3;
    const uint4* hp = (const uint4*)(h2b + (size_t)node * 64);
    const float* wsp = wts + head * 64;
    const float* wdp = wtd + head * 64;
    float s = 0.f, d = 0.f;
#pragma unroll
    for (int cq = 0; cq < 8; cq++) {
        uint4 q = hp[cq];
        float f0 = bflo(q.x), f1 = bfhi(q.x), f2 = bflo(q.y), f3 = bfhi(q.y);
        float f4 = bflo(q.z), f5 = bfhi(q.z), f6 = bflo(q.w), f7 = bfhi(q.w);
        int c = cq * 8;
        s += f0 * wsp[c] + f1 * wsp[c + 1] + f2 * wsp[c + 2] + f3 * wsp[c + 3]
           + f4 * wsp[c + 4] + f5 * wsp[c + 5] + f6 * wsp[c + 6] + f7 * wsp[c + 7];
        d += f0 * wdp[c] + f1 * wdp[c + 1] + f2 * wdp[c + 2] + f3 * wdp[c + 3]
           + f4 * wdp[c + 4] + f5 * wdp[c + 5] + f6 * wdp[c + 6] + f7 * wdp[c + 7];
    }
    als[i] = s; ald[i] = d;
}

// ---------------- CSR build ----------------
__global__ __launch_bounds__(256) void csr_hist(
    const int* __restrict__ ei, int E, int Etot, int* __restrict__ deg)
{
    int e = blockIdx.x * blockDim.x + threadIdx.x;
    if (e >= Etot) return;
    int d = (e < E) ? ei[E + e] : e - E;
    atomicAdd(&deg[d], 1);
}

// ---- parallel 3-stage exclusive scan of deg -> rowptr/cursor ----
__global__ __launch_bounds__(256) void scan_partial(
    const int* __restrict__ deg, int* __restrict__ bsum, int N)
{
    __shared__ int red[256];
    int base = blockIdx.x * 1024;
    int t = threadIdx.x;
    int i0 = base + t * 4;
    int s = 0;
    if (i0 + 3 < N) {
        int4 v = *(const int4*)&deg[i0];
        s = v.x + v.y + v.z + v.w;
    } else {
#pragma unroll
        for (int j = 0; j < 4; j++) if (i0 + j < N) s += deg[i0 + j];
    }
    red[t] = s;
    __syncthreads();
    for (int off = 128; off; off >>= 1) {
        if (t < off) red[t] += red[t + off];
        __syncthreads();
    }
    if (t == 0) bsum[blockIdx.x] = red[0];
}

__global__ __launch_bounds__(64) void scan_bsums(
    const int* __restrict__ bsum, int* __restrict__ boff,
    int* __restrict__ rowptr, int nb, int N)
{
    __shared__ int sh[256];
    int t = threadIdx.x;
    for (int i = t; i < nb; i += 64) sh[i] = bsum[i];
    __syncthreads();
    if (t == 0) {
        int run = 0;
        for (int i = 0; i < nb; i++) { int x = sh[i]; sh[i] = run; run += x; }
        rowptr[N] = run;
    }
    __syncthreads();
    for (int i = t; i < nb; i += 64) boff[i] = sh[i];
}

__global__ __launch_bounds__(256) void scan_final(
    const int* __restrict__ deg, const int* __restrict__ boff,
    int* __restrict__ rowptr, int* __restrict__ cursor, int N)
{
    __shared__ int red[256];
    int base = blockIdx.x * 1024;
    int t = threadIdx.x;
    int i0 = base + t * 4;
    int v0 = 0, v1 = 0, v2 = 0, v3 = 0;
    if (i0 + 3 < N) {
        int4 v = *(const int4*)&deg[i0];
        v0 = v.x; v1 = v.y; v2 = v.z; v3 = v.w;
    } else {
        if (i0 < N) v0 = deg[i0];
        if (i0 + 1 < N) v1 = deg[i0 + 1];
        if (i0 + 2 < N) v2 = deg[i0 + 2];
        if (i0 + 3 < N) v3 = deg[i0 + 3];
    }
    red[t] = v0 + v1 + v2 + v3;
    __syncthreads();
    for (int off = 1; off < 256; off <<= 1) {
        int n = (t >= off) ? red[t - off] : 0;
        __syncthreads();
        red[t] += n;
        __syncthreads();
    }
    int excl = (t ? red[t - 1] : 0) + boff[blockIdx.x];
    if (i0 < N)     { rowptr[i0] = excl;     cursor[i0] = excl; }
    excl += v0;
    if (i0 + 1 < N) { rowptr[i0 + 1] = excl; cursor[i0 + 1] = excl; }
    excl += v1;
    if (i0 + 2 < N) { rowptr[i0 + 2] = excl; cursor[i0 + 2] = excl; }
    excl += v2;
    if (i0 + 3 < N) { rowptr[i0 + 3] = excl; cursor[i0 + 3] = excl; }
}

__global__ __launch_bounds__(256) void csr_fill(
    const int* __restrict__ ei, int E, int Etot,
    int* __restrict__ cursor, int* __restrict__ esrc)
{
    int e = blockIdx.x * blockDim.x + threadIdx.x;
    if (e >= Etot) return;
    int s, d;
    if (e < E) { s = ei[e]; d = ei[E + e]; } else { s = d = e - E; }
    int pos = atomicAdd(&cursor[d], 1);
    esrc[pos] = s;
}

// ---------------- fused gather layer (C=64, bf16 rows): 1 wave per block,
// depth-1 pipelined, no-max softmax + bias + ELU ----------------
template <bool OUT_BF16>
__global__ __launch_bounds__(64) void gat_gather64(
    const int* __restrict__ rowptr, const int* __restrict__ esrc,
    const float* __restrict__ als, const float* __restrict__ ald,
    const ushort* __restrict__ hb, const float* __restrict__ bias,
    float* __restrict__ outf, ushort* __restrict__ outb, int N)
{
    int node = blockIdx.x;
    if (node >= N) return;
    int lane = threadIdx.x;
    int head = lane >> 3;
    int start = rowptr[node];
    int cnt = rowptr[node + 1] - start;
    float aldv = ald[(size_t)node * 8 + head];
    const int* ip = esrc + start;

    float dA = 0.f, aA = 0.f;
    float dB = 0.f, aB = 0.f;

    auto idx4 = [&](int k) {
        int4 r; r.x = ip[k]; r.y = ip[k + 1]; r.z = ip[k + 2]; r.w = ip[k + 3];
        return r;
    };
    auto issue = [&](int4 s, float4& ee, float4& hh) {
        ee.x = als[(size_t)s.x * 8 + head];
        ee.y = als[(size_t)s.y * 8 + head];
        ee.z = als[(size_t)s.z * 8 + head];
        ee.w = als[(size_t)s.w * 8 + head];
        hh.x = bf1(hb[(size_t)s.x * 64 + lane]);
        hh.y = bf1(hb[(size_t)s.y * 64 + lane]);
        hh.z = bf1(hb[(size_t)s.z * 64 + lane]);
        hh.w = bf1(hb[(size_t)s.w * 64 + lane]);
    };
    auto lrelu = [&](float e, int k) {
        e += aldv;
        e = (e > 0.f) ? e : NEG_SLOPE * e;
        return (k < cnt) ? e : -1e30f;
    };
    auto upd = [&](int base, float4 ee, float4 hh) {
        if (base >= cnt) return;
        float x0 = __expf(lrelu(ee.x, base + 0));
        float x1 = __expf(lrelu(ee.y, base + 1));
        float x2 = __expf(lrelu(ee.z, base + 2));
        float x3 = __expf(lrelu(ee.w, base + 3));
        dA += x0; aA = fmaf(x0, hh.x, aA);
        dA += x1; aA = fmaf(x1, hh.y, aA);
        dB += x2; aB = fmaf(x2, hh.z, aB);
        dB += x3; aB = fmaf(x3, hh.w, aB);
    };

    int4 i0 = idx4(0), i1 = idx4(4);
    float4 e0, h0, e1, h1;
    issue(i0, e0, h0);
    int nb = (cnt + 3) >> 2;
    for (int b = 0; b < nb; b += 2) {
        i0 = idx4((b + 2) * 4);
        issue(i1, e1, h1);
        upd(b * 4, e0, h0);
        i1 = idx4((b + 3) * 4);
        issue(i0, e0, h0);
        upd((b + 1) * 4, e1, h1);
    }
    float den = dA + dB;
    float acc = aA + aB;
    float v = acc / (den + 1e-16f) + bias[lane];
    v = (v > 0.f) ? v : (__expf(v) - 1.f);
    if (OUT_BF16) outb[(size_t)node * 64 + lane] = (ushort)bf16rne(v);
    else outf[(size_t)node * 64 + lane] = v;
}

// ---------------- layer 3: 1 wave per block, depth-1 pipelined gather of bf16
// h3p rows, no-max softmax, head-mean + bias + log_softmax ----------------
__global__ __launch_bounds__(64) void gat_l3_final(
    const int* __restrict__ rowptr, const int* __restrict__ esrc,
    const float* __restrict__ als, const float* __restrict__ ald,
    const ushort* __restrict__ h3pb, const float* __restrict__ b3,
    float* __restrict__ out, int N)
{
    int node = blockIdx.x;
    if (node >= N) return;
    int lane = threadIdx.x;
    int h = lane >> 3, c8 = lane & 7;
    int loff = h * 32 + c8 * 4;
    int start = rowptr[node];
    int cnt = rowptr[node + 1] - start;
    float aldv = ald[(size_t)node * 8 + h];
    const int* ip = esrc + start;

    float dA = 0.f, dB = 0.f;
    float4 accA = {0, 0, 0, 0}, accB = {0, 0, 0, 0};

    auto idx4 = [&](int k) {
        int4 r; r.x = ip[k]; r.y = ip[k + 1]; r.z = ip[k + 2]; r.w = ip[k + 3];
        return r;
    };
    auto issue = [&](int4 s, float4& ee, uint2& q0, uint2& q1, uint2& q2, uint2& q3) {
        ee.x = als[(size_t)s.x * 8 + h];
        ee.y = als[(size_t)s.y * 8 + h];
        ee.z = als[(size_t)s.z * 8 + h];
        ee.w = als[(size_t)s.w * 8 + h];
        q0 = *(const uint2*)&h3pb[(size_t)s.x * 256 + loff];
        q1 = *(const uint2*)&h3pb[(size_t)s.y * 256 + loff];
        q2 = *(const uint2*)&h3pb[(size_t)s.z * 256 + loff];
        q3 = *(const uint2*)&h3pb[(size_t)s.w * 256 + loff];
    };
    auto lrelu = [&](float e, int k) {
        e += aldv;
        e = (e > 0.f) ? e : NEG_SLOPE * e;
        return (k < cnt) ? e : -1e30f;
    };
    auto upedge = [&](float ee, uint2 q, float& d, float4& a) {
        d += ee;
        a.x = fmaf(ee, bflo(q.x), a.x);
        a.y = fmaf(ee, bfhi(q.x), a.y);
        a.z = fmaf(ee, bflo(q.y), a.z);
        a.w = fmaf(ee, bfhi(q.y), a.w);
    };
    auto upd = [&](int base, float4 ee, uint2 q0, uint2 q1, uint2 q2, uint2 q3) {
        if (base >= cnt) return;
        float x0 = __expf(lrelu(ee.x, base + 0));
        float x1 = __expf(lrelu(ee.y, base + 1));
        float x2 = __expf(lrelu(ee.z, base + 2));
        float x3 = __expf(lrelu(ee.w, base + 3));
        upedge(x0, q0, dA, accA);
        upedge(x1, q1, dA, accA);
        upedge(x2, q2, dB, accB);
        upedge(x3, q3, dB, accB);
    };

    int4 i0 = idx4(0), i1 = idx4(4);
    float4 eC, eD;
    uint2 q0C, q1C, q2C, q3C, q0D, q1D, q2D, q3D;
    issue(i0, eC, q0C, q1C, q2C, q3C);
    int nb = (cnt + 3) >> 2;
    for (int b = 0; b < nb; b += 2) {
        i0 = idx4((b + 2) * 4);
        issue(i1, eD, q0D, q1D, q2D, q3D);
        upd(b * 4, eC, q0C, q1C, q2C, q3C);
        i1 = idx4((b + 3) * 4);
        issue(i0, eC, q0C, q1C, q2C, q3C);
        upd((b + 1) * 4, eD, q0D, q1D, q2D, q3D);
    }

    float den = dA + dB;
    float inv = 1.f / (den + 1e-16f);
    float4 v;
    v.x = (accA.x + accB.x) * inv;
    v.y = (accA.y + accB.y) * inv;
    v.z = (accA.z + accB.z) * inv;
    v.w = (accA.w + accB.w) * inv;

#pragma unroll
    for (int o = 8; o < 64; o <<= 1) {
        v.x += __shfl_xor(v.x, o, 64);
        v.y += __shfl_xor(v.y, o, 64);
        v.z += __shfl_xor(v.z, o, 64);
        v.w += __shfl_xor(v.w, o, 64);
    }
    int cq = c8 * 4;
    v.x = v.x * 0.125f + b3[cq + 0];
    v.y = v.y * 0.125f + b3[cq + 1];
    v.z = v.z * 0.125f + b3[cq + 2];
    v.w = v.w * 0.125f + b3[cq + 3];
    float mx = fmaxf(fmaxf(v.x, v.y), fmaxf(v.z, v.w));
#pragma unroll
    for (int o = 1; o < 8; o <<= 1) mx = fmaxf(mx, __shfl_xor(mx, o, 64));
    float ex = __expf(v.x - mx) + __expf(v.y - mx) + __expf(v.z - mx) + __expf(v.w - mx);
#pragma unroll
    for (int o = 1; o < 8; o <<= 1) ex += __shfl_xor(ex, o, 64);
    float lse = mx + __logf(ex);
    if (lane < 8) {
        float4 r4 = {v.x - lse, v.y - lse, v.z - lse, v.w - lse};
        *(float4*)&out[(size_t)node * 32 + cq] = r4;
    }
}

// ---------------- host launch ----------------
extern "C" void kernel_launch(void* const* d_in, const int* in_sizes, int n_in,
                              void* d_out, int out_size, void* d_ws, size_t ws_size,
                              hipStream_t stream)
{
    const float* x   = (const float*)d_in[0];
    const int*   ei  = (const int*)  d_in[1];
    const float* W1  = (const float*)d_in[2];
    const float* as1 = (const float*)d_in[3];
    const float* ad1 = (const float*)d_in[4];
    const float* b1  = (const float*)d_in[5];
    const float* W2  = (const float*)d_in[6];
    const float* as2 = (const float*)d_in[7];
    const float* ad2 = (const float*)d_in[8];
    const float* b2  = (const float*)d_in[9];
    const float* W3  = (const float*)d_in[10];
    const float* as3 = (const float*)d_in[11];
    const float* ad3 = (const float*)d_in[12];
    const float* b3  = (const float*)d_in[13];
    float* out = (float*)d_out;

    const int N = in_sizes[0] / DIM_IN;
    const int E = in_sizes[1] / 2;
    const int Etot = E + N;

    float* ws = (float*)d_ws;
    size_t o = 0;
    float* p2  = ws + o; o += (size_t)N * 64;                // x@W2a (f32)
    float* h1  = ws + o; o += (size_t)N * 64;                // layer-1 out (f32)
    ushort* hp1b  = (ushort*)(ws + o); o += (size_t)N * 32;  // x@W1 (bf16)
    ushort* h2pb  = (ushort*)(ws + o); o += (size_t)N * 32;  // h2pre (bf16)
    ushort* h2b   = (ushort*)(ws + o); o += (size_t)N * 32;  // layer-2 out (bf16)
    ushort* h3pb  = (ushort*)(ws + o); o += (size_t)N * 128; // h2@W3 (bf16)
    float* als = ws + o; o += (size_t)N * 8;
    float* ald = ws + o; o += (size_t)N * 8;
    float* wts = ws + o; o += 512;
    float* wtd = ws + o; o += 512;
    ushort* wpack  = (ushort*)(ws + o); o += 65536;          // 131072 ushorts
    ushort* w3pack = (ushort*)(ws + o); o += 8192;           // 16384 ushorts
    int* deg    = (int*)(ws + o); o += N;
    int* rowptr = (int*)(ws + o); o += N + 1;
    int* cursor = (int*)(ws + o); o += N;
    int* bsum   = (int*)(ws + o); o += 64;
    int* boff   = (int*)(ws + o); o += 64;
    int* esrc   = (int*)(ws + o); o += Etot + EPAD;
    if (o * 4 > ws_size) return;  // workspace too small -> visible failure

    const int TB = 256;
    const int EG = (Etot + TB - 1) / TB;
    const int NB = (N + 1023) / 1024;

    pack_all<<<74, TB, 0, stream>>>(W1, W2, W3, as3, ad3, wpack, w3pack, wts, wtd);
    gemm1_mfma<<<(N + 63) / 64, TB, 0, stream>>>(x, wpack, hp1b, p2, N);

    zero_init<<<(N + TB - 1) / TB, TB, 0, stream>>>(deg, esrc + Etot, N);
    csr_hist<<<EG, TB, 0, stream>>>(ei, E, Etot, deg);
    scan_partial<<<NB, TB, 0, stream>>>(deg, bsum, N);
    scan_bsums<<<1, 64, 0, stream>>>(bsum, boff, rowptr, NB, N);
    scan_final<<<NB, TB, 0, stream>>>(deg, boff, rowptr, cursor, N);
    csr_fill<<<EG, TB, 0, stream>>>(ei, E, Etot, cursor, esrc);

    // ---- layer 1 ----
    attn_dots_b8<<<(N * 8 + TB - 1) / TB, TB, 0, stream>>>(hp1b, as1, ad1, als, ald, N * 8);
    gat_gather64<false><<<N, 64, 0, stream>>>(rowptr, esrc, als, ald, hp1b, b1, h1, nullptr, N);

    // h2pre = bf16(p2 + h1 @ W2[1000:1064])
    gemm_k64_n64_acc<<<(N + 15) / 16, TB, 0, stream>>>(h1, W2 + (size_t)DIM_IN * 64, p2, h2pb, N);

    // ---- layer 2 (bf16 in/out) ----
    attn_dots_b8<<<(N * 8 + TB - 1) / TB, TB, 0, stream>>>(h2pb, as2, ad2, als, ald, N * 8);
    gat_gather64<true><<<N, 64, 0, stream>>>(rowptr, esrc, als, ald, h2pb, b2, nullptr, h2b, N);

    // ---- layer 3 ----
    gemm3_mfma<<<(N + 15) / 16, TB, 0, stream>>>(h2b, w3pack, h3pb, N);
    attn_dots_w<<<(N * 8 + TB - 1) / TB, TB, 0, stream>>>(h2b, wts, wtd, als, ald, N * 8);
    gat_l3_final<<<N, 64, 0, stream>>>(rowptr, esrc, als, ald, h3pb, b3, out, N);
}

// Round 15
// 400.554 us; speedup vs baseline: 1.0258x; 1.0258x over previous
//
#include <hip/hip_runtime.h>
#include <hip/hip_bf16.h>

// ---------------- constants (match reference) ----------------
#define DIM_IN 1000
#define HEADS 8
#define HID 8
#define DIM_OUT 32
#define NEG_SLOPE 0.2f
#define EPAD 64

typedef __attribute__((ext_vector_type(4))) float f32x4;
typedef __attribute__((ext_vector_type(8))) short s16x8;

__device__ __forceinline__ unsigned bf16rne(float f) {
    unsigned u = __float_as_uint(f);
    return (u + 0x7FFFu + ((u >> 16) & 1u)) >> 16;
}
__device__ __forceinline__ unsigned pack2(float lo, float hi) {
    return bf16rne(lo) | (bf16rne(hi) << 16);
}
__device__ __forceinline__ float bflo(unsigned u) { return __uint_as_float(u << 16); }
__device__ __forceinline__ float bfhi(unsigned u) { return __uint_as_float(u & 0xFFFF0000u); }
__device__ __forceinline__ float bf1(ushort u) { return __uint_as_float((unsigned)u << 16); }

// ---------------- fused pre-pack: wpack (64 blk) | w3pack (8 blk) | wtilde (2 blk) ----
__global__ __launch_bounds__(256) void pack_all(
    const float* __restrict__ W1, const float* __restrict__ W2,
    const float* __restrict__ W3, const float* __restrict__ as3,
    const float* __restrict__ ad3, ushort* __restrict__ wpack,
    ushort* __restrict__ w3pack, float* __restrict__ wts,
    float* __restrict__ wtd)
{
    int b = blockIdx.x;
    if (b < 64) {
        int t = b * 256 + threadIdx.x;   // 0..16383
        int lane = t & 63;
        int ctg = (t >> 6) & 7;
        int kt = t >> 9;
        int c = ctg * 16 + (lane & 15);
        int kbase = kt * 32 + (lane >> 4) * 8;
        ushort v[8] __attribute__((aligned(16)));
#pragma unroll
        for (int j = 0; j < 8; j++) {
            int k = kbase + j;
            float w = 0.f;
            if (k < DIM_IN) w = (c < 64) ? W1[(size_t)k * 64 + c] : W2[(size_t)k * 64 + (c - 64)];
            v[j] = (ushort)bf16rne(w);
        }
        *(uint4*)&wpack[(size_t)t * 8] = *(const uint4*)v;
    } else if (b < 72) {
        int t = (b - 64) * 256 + threadIdx.x;   // 0..2047
        int lane = t & 63;
        int ctg = (t >> 6) & 15;
        int kt = t >> 10;
        int c = ctg * 16 + (lane & 15);
        int kbase = kt * 32 + (lane >> 4) * 8;
        ushort v[8] __attribute__((aligned(16)));
#pragma unroll
        for (int j = 0; j < 8; j++)
            v[j] = (ushort)bf16rne(W3[(size_t)(kbase + j) * 256 + c]);
        *(uint4*)&w3pack[(size_t)t * 8] = *(const uint4*)v;
    } else {
        int t = (b - 72) * 256 + threadIdx.x;   // 0..511
        if (t >= 512) return;
        int h = t >> 6, k = t & 63;
        float s = 0.f, d = 0.f;
#pragma unroll
        for (int c = 0; c < 32; c++) {
            float w = W3[(size_t)k * 256 + h * 32 + c];
            s += w * as3[h * 32 + c];
            d += w * ad3[h * 32 + c];
        }
        wts[h * 64 + k] = s;
        wtd[h * 64 + k] = d;
    }
}

// ---------------- zero deg + esrc pad in one launch ----------------
__global__ __launch_bounds__(256) void zero_init(
    int* __restrict__ deg, int* __restrict__ esrc_pad, int N)
{
    int i = blockIdx.x * 256 + threadIdx.x;
    if (i < N) deg[i] = 0;
    if (i < EPAD) esrc_pad[i] = 0;
}

// ---------------- GEMM1 (MFMA bf16): x[N,1000] @ [W1|W2a] -> hp1b(bf16), p2(f32) ----
// 32-row tile, 4 waves; wave wc: 32 rows x cols [wc*32, wc*32+32). 1563 blocks.
__global__ __launch_bounds__(256) void gemm1_mfma(
    const float* __restrict__ x, const ushort* __restrict__ wpack,
    ushort* __restrict__ hp1b, float* __restrict__ p2, int N)
{
    __shared__ __align__(16) ushort a_lds[2][32 * 32];   // 2 KB per buffer
    const int tid = threadIdx.x;
    const int lane = tid & 63;
    const int wc = tid >> 6;
    const int rowbase = blockIdx.x * 32;

    // staging: thread -> (row = tid>>3, kq = (tid&7)*4), one float4
    const int srow = tid >> 3;
    const int skq = (tid & 7) * 4;
    const int sgr = rowbase + srow;
    const int sidx = ((srow >> 4) * 64 + (skq >> 3) * 16 + (srow & 15)) * 8 + (skq & 4);

    f32x4 acc[2][2];
#pragma unroll
    for (int i = 0; i < 2; i++)
#pragma unroll
        for (int j = 0; j < 2; j++) acc[i][j] = (f32x4){0.f, 0.f, 0.f, 0.f};

    float4 s0;
    auto load_stage = [&](int t) {
        int k0 = t * 32 + skq;
        s0 = make_float4(0.f, 0.f, 0.f, 0.f);
        if (sgr < N && k0 + 4 <= DIM_IN)
            s0 = *(const float4*)&x[(size_t)sgr * DIM_IN + k0];
    };
    auto store_stage = [&](int buf) {
        uint2 w;
        w.x = pack2(s0.x, s0.y);
        w.y = pack2(s0.z, s0.w);
        *(uint2*)&a_lds[buf][sidx] = w;
    };

    load_stage(0);
    store_stage(0);
    __syncthreads();

    const s16x8* wp = (const s16x8*)wpack;
    for (int t = 0; t < 32; t++) {
        int cur = t & 1;
        if (t + 1 < 32) load_stage(t + 1);        // global prefetch (hidden under MFMA)
        s16x8 bf0 = wp[(size_t)(t * 8 + wc * 2 + 0) * 64 + lane];
        s16x8 bf1 = wp[(size_t)(t * 8 + wc * 2 + 1) * 64 + lane];
        s16x8 af0 = *(const s16x8*)&a_lds[cur][(0 * 64 + lane) * 8];
        s16x8 af1 = *(const s16x8*)&a_lds[cur][(1 * 64 + lane) * 8];
        acc[0][0] = __builtin_amdgcn_mfma_f32_16x16x32_bf16(af0, bf0, acc[0][0], 0, 0, 0);
        acc[0][1] = __builtin_amdgcn_mfma_f32_16x16x32_bf16(af0, bf1, acc[0][1], 0, 0, 0);
        acc[1][0] = __builtin_amdgcn_mfma_f32_16x16x32_bf16(af1, bf0, acc[1][0], 0, 0, 0);
        acc[1][1] = __builtin_amdgcn_mfma_f32_16x16x32_bf16(af1, bf1, acc[1][1], 0, 0, 0);
        if (t + 1 < 32) store_stage(cur ^ 1);
        __syncthreads();
    }

    // epilogue: C/D mapping col=lane&15, row=(lane>>4)*4+reg  [m89-verified]
    const int colbase = wc * 32;
#pragma unroll
    for (int rt = 0; rt < 2; rt++) {
        int gr = rowbase + rt * 16 + ((lane >> 4) * 4);
#pragma unroll
        for (int ctl = 0; ctl < 2; ctl++) {
            int c = colbase + ctl * 16 + (lane & 15);
#pragma unroll
            for (int reg = 0; reg < 4; reg++) {
                int r = gr + reg;
                if (r >= N) continue;
                float v = acc[rt][ctl][reg];
                if (c < 64) hp1b[(size_t)r * 64 + c] = (ushort)bf16rne(v);
                else        p2[(size_t)r * 64 + (c - 64)] = v;
            }
        }
    }
}

// ---------------- GEMM3 (MFMA bf16): h3pb[N,256] = h2b[N,64] @ W3 ----------------
__global__ __launch_bounds__(256) void gemm3_mfma(
    const ushort* __restrict__ h2b, const ushort* __restrict__ w3pack,
    ushort* __restrict__ h3pb, int N)
{
    const int tid = threadIdx.x;
    const int lane = tid & 63;
    const int wc = tid >> 6;
    const int rowbase = blockIdx.x * 16;
    const int arow = rowbase + (lane & 15);

    f32x4 acc[4];
#pragma unroll
    for (int i = 0; i < 4; i++) acc[i] = (f32x4){0.f, 0.f, 0.f, 0.f};

    const s16x8* wp = (const s16x8*)w3pack;
#pragma unroll
    for (int kt = 0; kt < 2; kt++) {
        s16x8 af = (s16x8){0, 0, 0, 0, 0, 0, 0, 0};
        if (arow < N)
            af = *(const s16x8*)&h2b[(size_t)arow * 64 + kt * 32 + (lane >> 4) * 8];
#pragma unroll
        for (int ct = 0; ct < 4; ct++) {
            s16x8 bf = wp[(size_t)(kt * 16 + wc * 4 + ct) * 64 + lane];
            acc[ct] = __builtin_amdgcn_mfma_f32_16x16x32_bf16(af, bf, acc[ct], 0, 0, 0);
        }
    }
#pragma unroll
    for (int ct = 0; ct < 4; ct++) {
        int col = wc * 64 + ct * 16 + (lane & 15);
        int gr = rowbase + (lane >> 4) * 4;
#pragma unroll
        for (int reg = 0; reg < 4; reg++) {
            int r = gr + reg;
            if (r < N) h3pb[(size_t)r * 256 + col] = (ushort)bf16rne(acc[ct][reg]);
        }
    }
}

// ---------------- small GEMM, K=64, NC=64: h2pre_b = bf16(p2 + h1@W2b) ----------------
__global__ __launch_bounds__(256) void gemm_k64_n64_acc(
    const float* __restrict__ A, const float* __restrict__ W,
    const float* __restrict__ P, ushort* __restrict__ outb, int N)
{
    __shared__ float as_[16][65];
    const int tid = threadIdx.x;
    const int rb = blockIdx.x * 16;
#pragma unroll
    for (int i = 0; i < 4; i++) {
        int idx = tid + i * 256;
        int r = idx >> 6, c = idx & 63;
        int gr = rb + r;
        as_[r][c] = (gr < N) ? A[(size_t)gr * 64 + c] : 0.f;
    }
    __syncthreads();
    const int row = tid >> 4;
    const int col = (tid & 15) * 4;
    float4 acc = {0, 0, 0, 0};
#pragma unroll 8
    for (int k = 0; k < 64; k++) {
        float a = as_[row][k];
        float4 w = *(const float4*)&W[k * 64 + col];
        acc.x += a * w.x; acc.y += a * w.y; acc.z += a * w.z; acc.w += a * w.w;
    }
    int gr = rb + row;
    if (gr < N) {
        float4 p = *(const float4*)&P[(size_t)gr * 64 + col];
        float v0 = p.x + acc.x, v1 = p.y + acc.y, v2 = p.z + acc.z, v3 = p.w + acc.w;
        *(uint*)&outb[(size_t)gr * 64 + col] = pack2(v0, v1);
        *(uint*)&outb[(size_t)gr * 64 + col + 2] = pack2(v2, v3);
    }
}

// ---------------- attention dots, bf16 rows, per-head C=8 ----------------
__global__ __launch_bounds__(256) void attn_dots_b8(
    const ushort* __restrict__ hb, const float* __restrict__ a_s,
    const float* __restrict__ a_d, float* __restrict__ als,
    float* __restrict__ ald, int NH)
{
    int i = blockIdx.x * blockDim.x + threadIdx.x;   // node*8 + head
    if (i >= NH) return;
    int head = i & 7;
    uint4 q = *(const uint4*)&hb[(size_t)i * 8];
    float f[8] = {bflo(q.x), bfhi(q.x), bflo(q.y), bfhi(q.y),
                  bflo(q.z), bfhi(q.z), bflo(q.w), bfhi(q.w)};
    const float* ap = a_s + head * 8;
    const float* dp = a_d + head * 8;
    float s = 0.f, d = 0.f;
#pragma unroll
    for (int c = 0; c < 8; c++) { s += f[c] * ap[c]; d += f[c] * dp[c]; }
    als[i] = s; ald[i] = d;
}

// ---------------- layer-3 attention dots from bf16 h2 via wtilde ----------------
__global__ __launch_bounds__(256) void attn_dots_w(
    const ushort* __restrict__ h2b, const float* __restrict__ wts,
    const float* __restrict__ wtd, float* __restrict__ als,
    float* __restrict__ ald, int NH)
{
    int i = blockIdx.x * blockDim.x + threadIdx.x;
    if (i >= NH) return;
    int head = i & 7, node = i >> 3;
    const uint4* hp = (const uint4*)(h2b + (size_t)node * 64);
    const float* wsp = wts + head * 64;
    const float* wdp = wtd + head * 64;
    float s = 0.f, d = 0.f;
#pragma unroll
    for (int cq = 0; cq < 8; cq++) {
        uint4 q = hp[cq];
        float f0 = bflo(q.x), f1 = bfhi(q.x), f2 = bflo(q.y), f3 = bfhi(q.y);
        float f4 = bflo(q.z), f5 = bfhi(q.z), f6 = bflo(q.w), f7 = bfhi(q.w);
        int c = cq * 8;
        s += f0 * wsp[c] + f1 * wsp[c + 1] + f2 * wsp[c + 2] + f3 * wsp[c + 3]
           + f4 * wsp[c + 4] + f5 * wsp[c + 5] + f6 * wsp[c + 6] + f7 * wsp[c + 7];
        d += f0 * wdp[c] + f1 * wdp[c + 1] + f2 * wdp[c + 2] + f3 * wdp[c + 3]
           + f4 * wdp[c + 4] + f5 * wdp[c + 5] + f6 * wdp[c + 6] + f7 * wdp[c + 7];
    }
    als[i] = s; ald[i] = d;
}

// ---------------- CSR build ----------------
__global__ __launch_bounds__(256) void csr_hist(
    const int* __restrict__ ei, int E, int Etot, int* __restrict__ deg)
{
    int e = blockIdx.x * blockDim.x + threadIdx.x;
    if (e >= Etot) return;
    int d = (e < E) ? ei[E + e] : e - E;
    atomicAdd(&deg[d], 1);
}

// ---- parallel 3-stage exclusive scan of deg -> rowptr/cursor ----
__global__ __launch_bounds__(256) void scan_partial(
    const int* __restrict__ deg, int* __restrict__ bsum, int N)
{
    __shared__ int red[256];
    int base = blockIdx.x * 1024;
    int t = threadIdx.x;
    int i0 = base + t * 4;
    int s = 0;
    if (i0 + 3 < N) {
        int4 v = *(const int4*)&deg[i0];
        s = v.x + v.y + v.z + v.w;
    } else {
#pragma unroll
        for (int j = 0; j < 4; j++) if (i0 + j < N) s += deg[i0 + j];
    }
    red[t] = s;
    __syncthreads();
    for (int off = 128; off; off >>= 1) {
        if (t < off) red[t] += red[t + off];
        __syncthreads();
    }
    if (t == 0) bsum[blockIdx.x] = red[0];
}

__global__ __launch_bounds__(64) void scan_bsums(
    const int* __restrict__ bsum, int* __restrict__ boff,
    int* __restrict__ rowptr, int nb, int N)
{
    __shared__ int sh[256];
    int t = threadIdx.x;
    for (int i = t; i < nb; i += 64) sh[i] = bsum[i];
    __syncthreads();
    if (t == 0) {
        int run = 0;
        for (int i = 0; i < nb; i++) { int x = sh[i]; sh[i] = run; run += x; }
        rowptr[N] = run;
    }
    __syncthreads();
    for (int i = t; i < nb; i += 64) boff[i] = sh[i];
}

__global__ __launch_bounds__(256) void scan_final(
    const int* __restrict__ deg, const int* __restrict__ boff,
    int* __restrict__ rowptr, int* __restrict__ cursor, int N)
{
    __shared__ int red[256];
    int base = blockIdx.x * 1024;
    int t = threadIdx.x;
    int i0 = base + t * 4;
    int v0 = 0, v1 = 0, v2 = 0, v3 = 0;
    if (i0 + 3 < N) {
        int4 v = *(const int4*)&deg[i0];
        v0 = v.x; v1 = v.y; v2 = v.z; v3 = v.w;
    } else {
        if (i0 < N) v0 = deg[i0];
        if (i0 + 1 < N) v1 = deg[i0 + 1];
        if (i0 + 2 < N) v2 = deg[i0 + 2];
        if (i0 + 3 < N) v3 = deg[i0 + 3];
    }
    red[t] = v0 + v1 + v2 + v3;
    __syncthreads();
    for (int off = 1; off < 256; off <<= 1) {
        int n = (t >= off) ? red[t - off] : 0;
        __syncthreads();
        red[t] += n;
        __syncthreads();
    }
    int excl = (t ? red[t - 1] : 0) + boff[blockIdx.x];
    if (i0 < N)     { rowptr[i0] = excl;     cursor[i0] = excl; }
    excl += v0;
    if (i0 + 1 < N) { rowptr[i0 + 1] = excl; cursor[i0 + 1] = excl; }
    excl += v1;
    if (i0 + 2 < N) { rowptr[i0 + 2] = excl; cursor[i0 + 2] = excl; }
    excl += v2;
    if (i0 + 3 < N) { rowptr[i0 + 3] = excl; cursor[i0 + 3] = excl; }
}

__global__ __launch_bounds__(256) void csr_fill(
    const int* __restrict__ ei, int E, int Etot,
    int* __restrict__ cursor, int* __restrict__ esrc)
{
    int e = blockIdx.x * blockDim.x + threadIdx.x;
    if (e >= Etot) return;
    int s, d;
    if (e < E) { s = ei[e]; d = ei[E + e]; } else { s = d = e - E; }
    int pos = atomicAdd(&cursor[d], 1);
    esrc[pos] = s;
}

// ---------------- fused gather layer (C=64, bf16 rows): depth-1 pipelined,
// no-max softmax + bias + ELU ----------------
template <bool OUT_BF16>
__global__ __launch_bounds__(256) void gat_gather64(
    const int* __restrict__ rowptr, const int* __restrict__ esrc,
    const float* __restrict__ als, const float* __restrict__ ald,
    const ushort* __restrict__ hb, const float* __restrict__ bias,
    float* __restrict__ outf, ushort* __restrict__ outb, int N)
{
    int node = blockIdx.x * 4 + (threadIdx.x >> 6);
    if (node >= N) return;
    int lane = threadIdx.x & 63;
    int head = lane >> 3;
    int start = rowptr[node];
    int cnt = rowptr[node + 1] - start;
    float aldv = ald[(size_t)node * 8 + head];
    const int* ip = esrc + start;

    float dA = 0.f, aA = 0.f;
    float dB = 0.f, aB = 0.f;

    auto idx4 = [&](int k) {
        int4 r; r.x = ip[k]; r.y = ip[k + 1]; r.z = ip[k + 2]; r.w = ip[k + 3];
        return r;
    };
    auto issue = [&](int4 s, float4& ee, float4& hh) {
        ee.x = als[(size_t)s.x * 8 + head];
        ee.y = als[(size_t)s.y * 8 + head];
        ee.z = als[(size_t)s.z * 8 + head];
        ee.w = als[(size_t)s.w * 8 + head];
        hh.x = bf1(hb[(size_t)s.x * 64 + lane]);
        hh.y = bf1(hb[(size_t)s.y * 64 + lane]);
        hh.z = bf1(hb[(size_t)s.z * 64 + lane]);
        hh.w = bf1(hb[(size_t)s.w * 64 + lane]);
    };
    auto lrelu = [&](float e, int k) {
        e += aldv;
        e = (e > 0.f) ? e : NEG_SLOPE * e;
        return (k < cnt) ? e : -1e30f;
    };
    auto upd = [&](int base, float4 ee, float4 hh) {
        if (base >= cnt) return;
        float x0 = __expf(lrelu(ee.x, base + 0));
        float x1 = __expf(lrelu(ee.y, base + 1));
        float x2 = __expf(lrelu(ee.z, base + 2));
        float x3 = __expf(lrelu(ee.w, base + 3));
        dA += x0; aA = fmaf(x0, hh.x, aA);
        dA += x1; aA = fmaf(x1, hh.y, aA);
        dB += x2; aB = fmaf(x2, hh.z, aB);
        dB += x3; aB = fmaf(x3, hh.w, aB);
    };

    int4 i0 = idx4(0), i1 = idx4(4);
    float4 e0, h0, e1, h1;
    issue(i0, e0, h0);
    int nb = (cnt + 3) >> 2;
    for (int b = 0; b < nb; b += 2) {
        i0 = idx4((b + 2) * 4);
        issue(i1, e1, h1);
        upd(b * 4, e0, h0);
        i1 = idx4((b + 3) * 4);
        issue(i0, e0, h0);
        upd((b + 1) * 4, e1, h1);
    }
    float den = dA + dB;
    float acc = aA + aB;
    float v = acc / (den + 1e-16f) + bias[lane];
    v = (v > 0.f) ? v : (__expf(v) - 1.f);
    if (OUT_BF16) outb[(size_t)node * 64 + lane] = (ushort)bf16rne(v);
    else outf[(size_t)node * 64 + lane] = v;
}

// ---------------- layer 3: depth-1 pipelined gather of bf16 h3p rows,
// no-max softmax, head-mean + bias + log_softmax. One wave per node. ----------------
__global__ __launch_bounds__(256) void gat_l3_final(
    const int* __restrict__ rowptr, const int* __restrict__ esrc,
    const float* __restrict__ als, const float* __restrict__ ald,
    const ushort* __restrict__ h3pb, const float* __restrict__ b3,
    float* __restrict__ out, int N)
{
    int node = blockIdx.x * 4 + (threadIdx.x >> 6);
    if (node >= N) return;
    int lane = threadIdx.x & 63;
    int h = lane >> 3, c8 = lane & 7;
    int loff = h * 32 + c8 * 4;
    int start = rowptr[node];
    int cnt = rowptr[node + 1] - start;
    float aldv = ald[(size_t)node * 8 + h];
    const int* ip = esrc + start;

    float dA = 0.f, dB = 0.f;
    float4 accA = {0, 0, 0, 0}, accB = {0, 0, 0, 0};

    auto idx4 = [&](int k) {
        int4 r; r.x = ip[k]; r.y = ip[k + 1]; r.z = ip[k + 2]; r.w = ip[k + 3];
        return r;
    };
    auto issue = [&](int4 s, float4& ee, uint2& q0, uint2& q1, uint2& q2, uint2& q3) {
        ee.x = als[(size_t)s.x * 8 + h];
        ee.y = als[(size_t)s.y * 8 + h];
        ee.z = als[(size_t)s.z * 8 + h];
        ee.w = als[(size_t)s.w * 8 + h];
        q0 = *(const uint2*)&h3pb[(size_t)s.x * 256 + loff];
        q1 = *(const uint2*)&h3pb[(size_t)s.y * 256 + loff];
        q2 = *(const uint2*)&h3pb[(size_t)s.z * 256 + loff];
        q3 = *(const uint2*)&h3pb[(size_t)s.w * 256 + loff];
    };
    auto lrelu = [&](float e, int k) {
        e += aldv;
        e = (e > 0.f) ? e : NEG_SLOPE * e;
        return (k < cnt) ? e : -1e30f;
    };
    auto upedge = [&](float ee, uint2 q, float& d, float4& a) {
        d += ee;
        a.x = fmaf(ee, bflo(q.x), a.x);
        a.y = fmaf(ee, bfhi(q.x), a.y);
        a.z = fmaf(ee, bflo(q.y), a.z);
        a.w = fmaf(ee, bfhi(q.y), a.w);
    };
    auto upd = [&](int base, float4 ee, uint2 q0, uint2 q1, uint2 q2, uint2 q3) {
        if (base >= cnt) return;
        float x0 = __expf(lrelu(ee.x, base + 0));
        float x1 = __expf(lrelu(ee.y, base + 1));
        float x2 = __expf(lrelu(ee.z, base + 2));
        float x3 = __expf(lrelu(ee.w, base + 3));
        upedge(x0, q0, dA, accA);
        upedge(x1, q1, dA, accA);
        upedge(x2, q2, dB, accB);
        upedge(x3, q3, dB, accB);
    };

    int4 i0 = idx4(0), i1 = idx4(4);
    float4 eC, eD;
    uint2 q0C, q1C, q2C, q3C, q0D, q1D, q2D, q3D;
    issue(i0, eC, q0C, q1C, q2C, q3C);
    int nb = (cnt + 3) >> 2;
    for (int b = 0; b < nb; b += 2) {
        i0 = idx4((b + 2) * 4);
        issue(i1, eD, q0D, q1D, q2D, q3D);
        upd(b * 4, eC, q0C, q1C, q2C, q3C);
        i1 = idx4((b + 3) * 4);
        issue(i0, eC, q0C, q1C, q2C, q3C);
        upd((b + 1) * 4, eD, q0D, q1D, q2D, q3D);
    }

    float den = dA + dB;
    float inv = 1.f / (den + 1e-16f);
    float4 v;
    v.x = (accA.x + accB.x) * inv;
    v.y = (accA.y + accB.y) * inv;
    v.z = (accA.z + accB.z) * inv;
    v.w = (accA.w + accB.w) * inv;

#pragma unroll
    for (int o = 8; o < 64; o <<= 1) {
        v.x += __shfl_xor(v.x, o, 64);
        v.y += __shfl_xor(v.y, o, 64);
        v.z += __shfl_xor(v.z, o, 64);
        v.w += __shfl_xor(v.w, o, 64);
    }
    int cq = c8 * 4;
    v.x = v.x * 0.125f + b3[cq + 0];
    v.y = v.y * 0.125f + b3[cq + 1];
    v.z = v.z * 0.125f + b3[cq + 2];
    v.w = v.w * 0.125f + b3[cq + 3];
    float mx = fmaxf(fmaxf(v.x, v.y), fmaxf(v.z, v.w));
#pragma unroll
    for (int o = 1; o < 8; o <<= 1) mx = fmaxf(mx, __shfl_xor(mx, o, 64));
    float ex = __expf(v.x - mx) + __expf(v.y - mx) + __expf(v.z - mx) + __expf(v.w - mx);
#pragma unroll
    for (int o = 1; o < 8; o <<= 1) ex += __shfl_xor(ex, o, 64);
    float lse = mx + __logf(ex);
    if (lane < 8) {
        float4 r4 = {v.x - lse, v.y - lse, v.z - lse, v.w - lse};
        *(float4*)&out[(size_t)node * 32 + cq] = r4;
    }
}

// ---------------- host launch ----------------
extern "C" void kernel_launch(void* const* d_in, const int* in_sizes, int n_in,
                              void* d_out, int out_size, void* d_ws, size_t ws_size,
                              hipStream_t stream)
{
    const float* x   = (const float*)d_in[0];
    const int*   ei  = (const int*)  d_in[1];
    const float* W1  = (const float*)d_in[2];
    const float* as1 = (const float*)d_in[3];
    const float* ad1 = (const float*)d_in[4];
    const float* b1  = (const float*)d_in[5];
    const float* W2  = (const float*)d_in[6];
    const float* as2 = (const float*)d_in[7];
    const float* ad2 = (const float*)d_in[8];
    const float* b2  = (const float*)d_in[9];
    const float* W3  = (const float*)d_in[10];
    const float* as3 = (const float*)d_in[11];
    const float* ad3 = (const float*)d_in[12];
    const float* b3  = (const float*)d_in[13];
    float* out = (float*)d_out;

    const int N = in_sizes[0] / DIM_IN;
    const int E = in_sizes[1] / 2;
    const int Etot = E + N;

    float* ws = (float*)d_ws;
    size_t o = 0;
    float* p2  = ws + o; o += (size_t)N * 64;                // x@W2a (f32)
    float* h1  = ws + o; o += (size_t)N * 64;                // layer-1 out (f32)
    ushort* hp1b  = (ushort*)(ws + o); o += (size_t)N * 32;  // x@W1 (bf16)
    ushort* h2pb  = (ushort*)(ws + o); o += (size_t)N * 32;  // h2pre (bf16)
    ushort* h2b   = (ushort*)(ws + o); o += (size_t)N * 32;  // layer-2 out (bf16)
    ushort* h3pb  = (ushort*)(ws + o); o += (size_t)N * 128; // h2@W3 (bf16)
    float* als = ws + o; o += (size_t)N * 8;
    float* ald = ws + o; o += (size_t)N * 8;
    float* wts = ws + o; o += 512;
    float* wtd = ws + o; o += 512;
    ushort* wpack  = (ushort*)(ws + o); o += 65536;          // 131072 ushorts
    ushort* w3pack = (ushort*)(ws + o); o += 8192;           // 16384 ushorts
    int* deg    = (int*)(ws + o); o += N;
    int* rowptr = (int*)(ws + o); o += N + 1;
    int* cursor = (int*)(ws + o); o += N;
    int* bsum   = (int*)(ws + o); o += 64;
    int* boff   = (int*)(ws + o); o += 64;
    int* esrc   = (int*)(ws + o); o += Etot + EPAD;
    if (o * 4 > ws_size) return;  // workspace too small -> visible failure

    const int TB = 256;
    const int EG = (Etot + TB - 1) / TB;
    const int NB = (N + 1023) / 1024;

    pack_all<<<74, TB, 0, stream>>>(W1, W2, W3, as3, ad3, wpack, w3pack, wts, wtd);
    gemm1_mfma<<<(N + 31) / 32, TB, 0, stream>>>(x, wpack, hp1b, p2, N);

    zero_init<<<(N + TB - 1) / TB, TB, 0, stream>>>(deg, esrc + Etot, N);
    csr_hist<<<EG, TB, 0, stream>>>(ei, E, Etot, deg);
    scan_partial<<<NB, TB, 0, stream>>>(deg, bsum, N);
    scan_bsums<<<1, 64, 0, stream>>>(bsum, boff, rowptr, NB, N);
    scan_final<<<NB, TB, 0, stream>>>(deg, boff, rowptr, cursor, N);
    csr_fill<<<EG, TB, 0, stream>>>(ei, E, Etot, cursor, esrc);

    // ---- layer 1 ----
    attn_dots_b8<<<(N * 8 + TB - 1) / TB, TB, 0, stream>>>(hp1b, as1, ad1, als, ald, N * 8);
    gat_gather64<false><<<(N + 3) / 4, TB, 0, stream>>>(rowptr, esrc, als, ald, hp1b, b1, h1, nullptr, N);

    // h2pre = bf16(p2 + h1 @ W2[1000:1064])
    gemm_k64_n64_acc<<<(N + 15) / 16, TB, 0, stream>>>(h1, W2 + (size_t)DIM_IN * 64, p2, h2pb, N);

    // ---- layer 2 (bf16 in/out) ----
    attn_dots_b8<<<(N * 8 + TB - 1) / TB, TB, 0, stream>>>(h2pb, as2, ad2, als, ald, N * 8);
    gat_gather64<true><<<(N + 3) / 4, TB, 0, stream>>>(rowptr, esrc, als, ald, h2pb, b2, nullptr, h2b, N);

    // ---- layer 3 ----
    gemm3_mfma<<<(N + 15) / 16, TB, 0, stream>>>(h2b, w3pack, h3pb, N);
    attn_dots_w<<<(N * 8 + TB - 1) / TB, TB, 0, stream>>>(h2b, wts, wtd, als, ald, N * 8);
    gat_l3_final<<<(N + 3) / 4, TB, 0, stream>>>(rowptr, esrc, als, ald, h3pb, b3, out, N);
}